// Round 2
// baseline (144.977 us; speedup 1.0000x reference)
//
#include <hip/hip_runtime.h>

// GPLoss: gradient-profile loss, scalar output.
// ws layout: [0..32) bytes : 4 doubles {rowsum_v, rowsum_h, colsum_v, colsum_h}
//            [32 .. 32+96*8*6*512*4) : per-(plane,strip) column partials
//            float[96*8][6][512]  (f*3+q major: f=0 fv / f=1 fh; q=dot,sx,sr)

__device__ __forceinline__ float wave_sum_f(float v){
  #pragma unroll
  for (int m = 1; m < 64; m <<= 1) v += __shfl_xor(v, m, 64);
  return v;
}

__device__ __forceinline__ float cos_sim(float dot, float sx, float sr){
  float nx = fmaxf(sqrtf(sx), 1e-12f);
  float nr = fmaxf(sqrtf(sr), 1e-12f);
  return dot / (nx * nr);
}

__global__ __launch_bounds__(256) void gp_main(
    const float* __restrict__ X, const float* __restrict__ R,
    double* __restrict__ sums, float* __restrict__ colPart)
{
  const int bid = blockIdx.x;
  const int p = bid >> 3;      // plane 0..95
  const int s = bid & 7;       // strip 0..7 (64 rows each)
  const int tid = threadIdx.x;
  const int w = tid >> 6;      // wave 0..3
  const int l = tid & 63;

  const size_t plane = (size_t)p * (512u * 512u);
  const float* xp = X + plane;
  const float* rp = R + plane;

  const int base = s * 64 + w * 16;       // first row this wave owns
  const int hend = min(base + 16, 511);   // inclusive last row loaded

  // per-lane column accumulators: cols {4l..4l+3} (j=0..3) and {256+4l..} (j=4..7)
  float cfv0[8], cfv1[8], cfv2[8], cfh0[8], cfh1[8], cfh2[8];
  #pragma unroll
  for (int j = 0; j < 8; ++j){
    cfv0[j]=0.f; cfv1[j]=0.f; cfv2[j]=0.f;
    cfh0[j]=0.f; cfh1[j]=0.f; cfh2[j]=0.f;
  }
  float rowsum_v = 0.f, rowsum_h = 0.f;

  const int c0 = 4 * l;
  const int c1 = 256 + 4 * l;

  float4 px0 = make_float4(0.f,0.f,0.f,0.f), px1 = px0, pr0 = px0, pr1 = px0;

  for (int h = base; h <= hend; ++h){
    const float* xrow = xp + (size_t)h * 512;
    const float* rrow = rp + (size_t)h * 512;
    const float4 x0 = *(const float4*)(xrow + c0);
    const float4 x1 = *(const float4*)(xrow + c1);
    const float4 r0 = *(const float4*)(rrow + c0);
    const float4 r1 = *(const float4*)(rrow + c1);

    if (h > base){
      // f_h row (h-1): prev - cur, same columns, no cross-lane needed
      float dx[8], dr[8];
      dx[0]=px0.x-x0.x; dx[1]=px0.y-x0.y; dx[2]=px0.z-x0.z; dx[3]=px0.w-x0.w;
      dx[4]=px1.x-x1.x; dx[5]=px1.y-x1.y; dx[6]=px1.z-x1.z; dx[7]=px1.w-x1.w;
      dr[0]=pr0.x-r0.x; dr[1]=pr0.y-r0.y; dr[2]=pr0.z-r0.z; dr[3]=pr0.w-r0.w;
      dr[4]=pr1.x-r1.x; dr[5]=pr1.y-r1.y; dr[6]=pr1.z-r1.z; dr[7]=pr1.w-r1.w;
      float d=0.f, a=0.f, b=0.f;
      #pragma unroll
      for (int j = 0; j < 8; ++j){
        d = fmaf(dx[j], dr[j], d);
        a = fmaf(dx[j], dx[j], a);
        b = fmaf(dr[j], dr[j], b);
        cfh0[j] = fmaf(dx[j], dr[j], cfh0[j]);
        cfh1[j] = fmaf(dx[j], dx[j], cfh1[j]);
        cfh2[j] = fmaf(dr[j], dr[j], cfh2[j]);
      }
      d = wave_sum_f(d); a = wave_sum_f(a); b = wave_sum_f(b);
      rowsum_h += cos_sim(d, a, b);
    }

    if (h < base + 16){
      // f_v row h: cur[w] - cur[w+1]; lane-boundary neighbors via shfl
      const int nl = (l + 1) & 63;
      const float a0n  = __shfl(x0.x, nl, 64);   // x[4(l+1)]
      const float a1n  = __shfl(x1.x, nl, 64);   // x[256+4(l+1)]
      const float amid = __shfl(x1.x, 0, 64);    // x[256]
      const float b0n  = __shfl(r0.x, nl, 64);
      const float b1n  = __shfl(r1.x, nl, 64);
      const float bmid = __shfl(r1.x, 0, 64);
      const bool last = (l == 63);
      float dv[8], ev[8];
      dv[0]=x0.x-x0.y; dv[1]=x0.y-x0.z; dv[2]=x0.z-x0.w;
      dv[3]=x0.w - (last ? amid : a0n);
      dv[4]=x1.x-x1.y; dv[5]=x1.y-x1.z; dv[6]=x1.z-x1.w;
      dv[7]= last ? 0.f : (x1.w - a1n);           // col 511 excluded
      ev[0]=r0.x-r0.y; ev[1]=r0.y-r0.z; ev[2]=r0.z-r0.w;
      ev[3]=r0.w - (last ? bmid : b0n);
      ev[4]=r1.x-r1.y; ev[5]=r1.y-r1.z; ev[6]=r1.z-r1.w;
      ev[7]= last ? 0.f : (r1.w - b1n);
      float d=0.f, a=0.f, b=0.f;
      #pragma unroll
      for (int j = 0; j < 8; ++j){
        d = fmaf(dv[j], ev[j], d);
        a = fmaf(dv[j], dv[j], a);
        b = fmaf(ev[j], ev[j], b);
        cfv0[j] = fmaf(dv[j], ev[j], cfv0[j]);
        cfv1[j] = fmaf(dv[j], dv[j], cfv1[j]);
        cfv2[j] = fmaf(ev[j], ev[j], cfv2[j]);
      }
      d = wave_sum_f(d); a = wave_sum_f(a); b = wave_sum_f(b);
      rowsum_v += cos_sim(d, a, b);
    }

    px0 = x0; px1 = x1; pr0 = r0; pr1 = r1;
  }

  // block-level column reduction (4 waves -> one strip slot), atomic-free global
  __shared__ float lcol[6 * 512];   // 12 KB
  for (int i = tid; i < 6 * 512; i += 256) lcol[i] = 0.f;
  __syncthreads();
  #pragma unroll
  for (int j = 0; j < 4; ++j){
    atomicAdd(&lcol[0*512 + c0 + j], cfv0[j]);
    atomicAdd(&lcol[0*512 + c1 + j], cfv0[4+j]);
    atomicAdd(&lcol[1*512 + c0 + j], cfv1[j]);
    atomicAdd(&lcol[1*512 + c1 + j], cfv1[4+j]);
    atomicAdd(&lcol[2*512 + c0 + j], cfv2[j]);
    atomicAdd(&lcol[2*512 + c1 + j], cfv2[4+j]);
    atomicAdd(&lcol[3*512 + c0 + j], cfh0[j]);
    atomicAdd(&lcol[3*512 + c1 + j], cfh0[4+j]);
    atomicAdd(&lcol[4*512 + c0 + j], cfh1[j]);
    atomicAdd(&lcol[4*512 + c1 + j], cfh1[4+j]);
    atomicAdd(&lcol[5*512 + c0 + j], cfh2[j]);
    atomicAdd(&lcol[5*512 + c1 + j], cfh2[4+j]);
  }
  __syncthreads();
  float* slot = colPart + (size_t)bid * (6 * 512);
  for (int i = tid; i < 6 * 512; i += 256) slot[i] = lcol[i];

  if (l == 0){
    atomicAdd(&sums[0], (double)rowsum_v);
    atomicAdd(&sums[1], (double)rowsum_h);
  }
}

__global__ __launch_bounds__(256) void gp_cols(
    const float* __restrict__ colPart, double* __restrict__ sums)
{
  const int p = blockIdx.x;   // plane
  const int tid = threadIdx.x;
  double sv = 0.0, sh = 0.0;
  for (int idx = tid; idx < 1024; idx += 256){
    const int f = idx >> 9;      // 0 = fv cols, 1 = fh cols
    const int col = idx & 511;
    float d = 0.f, a = 0.f, b = 0.f;
    #pragma unroll
    for (int s = 0; s < 8; ++s){
      const float* slot = colPart + (size_t)((p*8 + s)*6 + f*3) * 512;
      d += slot[0*512 + col];
      a += slot[1*512 + col];
      b += slot[2*512 + col];
    }
    const float c = cos_sim(d, a, b);
    if (f == 0){ if (col < 511) sv += (double)c; }
    else sh += (double)c;
  }
  #pragma unroll
  for (int m = 1; m < 64; m <<= 1){
    sv += __shfl_xor(sv, m, 64);
    sh += __shfl_xor(sh, m, 64);
  }
  __shared__ double lsv[4], lsh[4];
  const int w = tid >> 6, l = tid & 63;
  if (l == 0){ lsv[w] = sv; lsh[w] = sh; }
  __syncthreads();
  if (tid == 0){
    atomicAdd(&sums[2], lsv[0]+lsv[1]+lsv[2]+lsv[3]);
    atomicAdd(&sums[3], lsh[0]+lsh[1]+lsh[2]+lsh[3]);
  }
}

__global__ void gp_fin(const double* __restrict__ sums, float* __restrict__ out){
  const double t = sums[0]/512.0 + sums[1]/511.0 + sums[2]/511.0 + sums[3]/512.0;
  out[0] = (float)(-t / 32.0);
}

extern "C" void kernel_launch(void* const* d_in, const int* in_sizes, int n_in,
                              void* d_out, int out_size, void* d_ws, size_t ws_size,
                              hipStream_t stream) {
  const float* X = (const float*)d_in[0];
  const float* R = (const float*)d_in[1];
  double* sums   = (double*)d_ws;
  float* colPart = (float*)((char*)d_ws + 32);

  hipMemsetAsync(d_ws, 0, 32, stream);               // zero the 4 double sums
  gp_main<<<dim3(96*8), dim3(256), 0, stream>>>(X, R, sums, colPart);
  gp_cols<<<dim3(96), dim3(256), 0, stream>>>(colPart, sums);
  gp_fin<<<dim3(1), dim3(1), 0, stream>>>(sums, (float*)d_out);
}